// Round 8
// baseline (138.914 us; speedup 1.0000x reference)
//
#include <hip/hip_runtime.h>
#include <hip/hip_fp16.h>
#include <math.h>

#define HW 512
#define LOG2HW 9
#define NIMG 96       // N*C = 32*3
#define NBANDS 16
#define NCOL 257      // rfft columns 0..256
#define PSTRIDE 518   // float2 stride per 512-FFT scratch slice in LDS
#define IMG_U4 (17 * 512 * 4)   // uint4 per image: [ct17][r512][slot4] (f16 complex)
#define PI_F 3.14159265358979323846f

union U32H2 { unsigned u; __half2 h; };

// ---------- small complex helpers ----------
__device__ __forceinline__ float2 cadd(float2 a, float2 b){return make_float2(a.x+b.x, a.y+b.y);}
__device__ __forceinline__ float2 csub(float2 a, float2 b){return make_float2(a.x-b.x, a.y-b.y);}
__device__ __forceinline__ float2 cmul(float2 a, float2 b){return make_float2(a.x*b.x - a.y*b.y, a.x*b.y + a.y*b.x);}
__device__ __forceinline__ float2 mul_negi(float2 a){return make_float2(a.y, -a.x);}  // a * (-i)

// octal digit reversal of 9-bit index (involution)
__device__ __forceinline__ int dr9(int p) {
    return ((p & 7) << 6) | (p & 56) | ((p >> 6) & 7);
}

// LDS scratch swizzle (involution, preserves low 2 bits)
__device__ __forceinline__ int swz(int i)  { return i ^ (((i >> 6) & 7) << 2); }

// 8-point DFT, W8 = e^{-2*pi*i/8}
__device__ __forceinline__ void dft8(const float2 u[8], float2 v[8]) {
    const float R = 0.70710678118654752440f;
    float2 s0 = cadd(u[0], u[4]), s1 = cadd(u[2], u[6]);
    float2 d0 = csub(u[0], u[4]), d1 = csub(u[2], u[6]);
    float2 E0 = cadd(s0, s1), E2 = csub(s0, s1);
    float2 ni = mul_negi(d1);
    float2 E1 = cadd(d0, ni), E3 = csub(d0, ni);
    float2 t0 = cadd(u[1], u[5]), t1 = cadd(u[3], u[7]);
    float2 e0 = csub(u[1], u[5]), e1 = csub(u[3], u[7]);
    float2 O0 = cadd(t0, t1), O2 = csub(t0, t1);
    float2 mi = mul_negi(e1);
    float2 O1 = cadd(e0, mi), O3 = csub(e0, mi);
    float2 w1O = make_float2(R * (O1.x + O1.y), R * (O1.y - O1.x));
    float2 w2O = mul_negi(O2);
    float2 w3O = make_float2(R * (O3.y - O3.x), -R * (O3.x + O3.y));
    v[0] = cadd(E0, O0);  v[4] = csub(E0, O0);
    v[1] = cadd(E1, w1O); v[5] = csub(E1, w1O);
    v[2] = cadd(E2, w2O); v[6] = csub(E2, w2O);
    v[3] = cadd(E3, w3O); v[7] = csub(E3, w3O);
}

__device__ __forceinline__ void twiddle_mul8(float2 v[8], float ang) {
    float sn, cs;
    __sincosf(ang, &sn, &cs);
    float2 w1 = make_float2(cs, sn);
    float2 w2 = cmul(w1, w1), w3 = cmul(w2, w1), w4 = cmul(w2, w2);
    float2 w5 = cmul(w3, w2), w6 = cmul(w3, w3), w7 = cmul(w4, w3);
    v[1] = cmul(v[1], w1); v[2] = cmul(v[2], w2); v[3] = cmul(v[3], w3);
    v[4] = cmul(v[4], w4); v[5] = cmul(v[5], w5); v[6] = cmul(v[6], w6);
    v[7] = cmul(v[7], w7);
}

// 512-pt DIF radix-8 FFT, one FFT per WAVE (lane j), wave-private LDS slice.
// Input: u[e] = x[j + 64e]. Output: v[s] = X[dr9(8j+s)]. No workgroup barriers.
__device__ __forceinline__ void fft512_wave(float2* zz, float2 u[8], float2 v[8], int j) {
    dft8(u, v);
    twiddle_mul8(v, -(2.0f * PI_F / 512.0f) * (float)j);
    #pragma unroll
    for (int s = 0; s < 8; ++s) zz[swz(j + 64 * s)] = v[s];
    __builtin_amdgcn_wave_barrier();
    const int sb = j >> 3, r = j & 7;
    #pragma unroll
    for (int e = 0; e < 8; ++e) u[e] = zz[swz(64 * sb + r + 8 * e)];
    __builtin_amdgcn_wave_barrier();
    dft8(u, v);
    twiddle_mul8(v, -(2.0f * PI_F / 64.0f) * (float)r);
    #pragma unroll
    for (int s = 0; s < 8; ++s) zz[swz(64 * sb + r + 8 * s)] = v[s];
    __builtin_amdgcn_wave_barrier();
    #pragma unroll
    for (int e = 0; e < 8; ++e) u[e] = zz[swz(8 * j + e)];
    __builtin_amdgcn_wave_barrier();
    dft8(u, v);
}

// ---------- weight precompute ----------
__global__ void wmapk_kernel(const float* __restrict__ bw,
                             const float* __restrict__ masks,
                             float* __restrict__ wmapk) {
    int idx = blockIdx.x * 256 + threadIdx.x;
    int k1 = idx >> LOG2HW, k2 = idx & (HW - 1);
    int p1 = (k1 + HW / 2) & (HW - 1);
    int p2 = (k2 + HW / 2) & (HW - 1);
    int off = p1 * HW + p2;
    float s = 0.f;
    #pragma unroll
    for (int b = 0; b < NBANDS; ++b)
        s += bw[b] * masks[b * HW * HW + off];
    wmapk[idx] = s;
}

// wfold_dr[c*512 + p]: Hermitian-folded weight for column c at storage
// position p (k1 = dr9(p)); includes ortho norm 1/512^2.
__global__ void wfold_kernel(const float* __restrict__ wmapk,
                             float* __restrict__ wfold_dr) {
    int idx = blockIdx.x * 256 + threadIdx.x;
    if (idx >= NCOL * HW) return;
    int c = idx >> LOG2HW, p = idx & (HW - 1);
    int k1 = dr9(p);
    float s = wmapk[k1 * HW + c];
    if (c >= 1 && c <= 255)
        s += wmapk[((HW - k1) & (HW - 1)) * HW + (HW - c)];
    wfold_dr[idx] = s * (1.0f / (512.0f * 512.0f));
}

// ---------- row pass (software-pipelined over NP=4 packs per wave) ----------
// Wave = packs f0..f0+3; pack f = image rows 2f (real) + 2f+1 (imag).
// Loads for pack p+1 are issued right after pack p's diff consumes the
// register buffer, so 8 KB/wave stays in flight under the FFT.
// Store layout matches colfft's tile: uint2 slot q = cp ^ ((r>>1)&7) within
// [ct][r]; the XOR keeps each lane's 4 pairs in one contiguous 32 B block,
// and rows 2f/2f+1 of the same wave complete each 128 B line (no RMW).
__global__ __launch_bounds__(256, 4)
void rowfft_kernel(const float* __restrict__ pred,
                   const float* __restrict__ gt,
                   uint4* __restrict__ fdata, int img0) {
    __shared__ float2 z[4 * PSTRIDE];
    const int limg = blockIdx.y;
    const int t = threadIdx.x;
    const int wv = t >> 6, j = t & 63;
    const int img = img0 + limg;
    const int f0 = blockIdx.x * 16 + wv * 4;

    float2* zz = z + wv * PSTRIDE;
    const float4* pp = (const float4*)(pred + ((size_t)img * HW + 2 * f0) * HW) + j;
    const float4* gp = (const float4*)(gt   + ((size_t)img * HW + 2 * f0) * HW) + j;
    uint4* img_base = fdata + (size_t)limg * IMG_U4;

    float4 rb[8];
    rb[0] = pp[0]; rb[1] = pp[64]; rb[2] = pp[128]; rb[3] = pp[192];
    rb[4] = gp[0]; rb[5] = gp[64]; rb[6] = gp[128]; rb[7] = gp[192];
    pp += 256; gp += 256;

    #pragma unroll
    for (int p = 0; p < 4; ++p) {
        const int f = f0 + p;
        // diff -> packed complex (re=row 2f, im=row 2f+1) in LDS
        {
            float4 a = rb[0], b = rb[4], d = rb[2], e4 = rb[6];
            float4* dst = (float4*)(zz + swz(4 * j));
            dst[0] = make_float4(a.x - b.x, d.x - e4.x, a.y - b.y, d.y - e4.y);
            dst[1] = make_float4(a.z - b.z, d.z - e4.z, a.w - b.w, d.w - e4.w);
            a = rb[1]; b = rb[5]; d = rb[3]; e4 = rb[7];
            dst = (float4*)(zz + swz(4 * (j + 64)));
            dst[0] = make_float4(a.x - b.x, d.x - e4.x, a.y - b.y, d.y - e4.y);
            dst[1] = make_float4(a.z - b.z, d.z - e4.z, a.w - b.w, d.w - e4.w);
        }
        __builtin_amdgcn_wave_barrier();
        if (p < 3) {   // issue next pack's loads; they fly under the FFT
            rb[0] = pp[0]; rb[1] = pp[64]; rb[2] = pp[128]; rb[3] = pp[192];
            rb[4] = gp[0]; rb[5] = gp[64]; rb[6] = gp[128]; rb[7] = gp[192];
            pp += 256; gp += 256;
        }

        float2 u[8], v[8];
        #pragma unroll
        for (int e = 0; e < 8; ++e) u[e] = zz[swz(j + 64 * e)];
        __builtin_amdgcn_wave_barrier();
        fft512_wave(zz, u, v, j);
        __builtin_amdgcn_wave_barrier();

        // natural-order bounce: Z[64s+m] = v[s]
        const int m = 8 * (j & 7) + (j >> 3);
        #pragma unroll
        for (int s = 0; s < 8; ++s) zz[swz(64 * s + m)] = v[s];
        __builtin_amdgcn_wave_barrier();

        // intra-wave Hermitian unpack: lanes 0..31 -> A-row (r=2f),
        // lanes 32..63 -> B-row (r=2f+1); lane owns c = 8*jj .. 8*jj+7.
        const int half = j >> 5, jj = j & 31;
        const int r = 2 * f + half;
        const int x = f & 7;               // (r>>1)&7
        float2 V[8];
        #pragma unroll
        for (int i = 0; i < 8; ++i) {
            int c = 8 * jj + i;
            float2 Zc = zz[swz(c)];
            float2 Zn = zz[swz((HW - c) & (HW - 1))];
            V[i] = (half == 0)
                 ? make_float2(0.5f * (Zc.x + Zn.x), 0.5f * (Zc.y - Zn.y))
                 : make_float2(0.5f * (Zc.y + Zn.y), 0.5f * (Zn.x - Zc.x));
        }
        uint2 pr[4];
        #pragma unroll
        for (int i2 = 0; i2 < 4; ++i2) {
            U32H2 aa, bb;
            aa.h = __floats2half2_rn(V[2 * i2].x, V[2 * i2].y);
            bb.h = __floats2half2_rn(V[2 * i2 + 1].x, V[2 * i2 + 1].y);
            pr[i2] = make_uint2(aa.u, bb.u);
        }
        // XOR-permute (x&3) via conditional swap layers (static indexing only)
        if (x & 1) { uint2 tmp = pr[0]; pr[0] = pr[1]; pr[1] = tmp;
                     tmp = pr[2]; pr[2] = pr[3]; pr[3] = tmp; }
        if (x & 2) { uint2 tmp = pr[0]; pr[0] = pr[2]; pr[2] = tmp;
                     tmp = pr[1]; pr[1] = pr[3]; pr[3] = tmp; }
        const int ct = jj >> 1;
        const int base2 = (4 * (jj & 1)) ^ (x & 4);   // uint2 slot 0 or 4
        uint4* dst = img_base + (size_t)(ct * 512 + r) * 4 + (base2 >> 1);
        dst[0] = make_uint4(pr[0].x, pr[0].y, pr[1].x, pr[1].y);
        dst[1] = make_uint4(pr[2].x, pr[2].y, pr[3].x, pr[3].y);
        if (jj == 0) {                      // c = 256 -> ct=16 slab, cp=0
            float2 Zc = zz[swz(256)];
            float vq = (half == 0) ? Zc.x : Zc.y;
            U32H2 hh; hh.h = __floats2half2_rn(vq, 0.f);
            uint2* d2 = (uint2*)(img_base + (size_t)(16 * 512 + r) * 4);
            d2[x] = make_uint2(hh.u, 0u);
        }
        __builtin_amdgcn_wave_barrier();
    }
}

// ---------- column pass (r7 structure, proven fast) ----------
__global__ __launch_bounds__(256)
void colfft_kernel(const uint4* __restrict__ fdata,
                   const float* __restrict__ wfold_dr,
                   float* __restrict__ partials, int img0) {
    __shared__ uint4 tile[2048];            // 32 KiB
    __shared__ float2 scr[4 * PSTRIDE];
    const int limg = blockIdx.y;
    const int ct = blockIdx.x;              // 0..16
    const int t = threadIdx.x;
    const int wv = t >> 6, j = t & 63;

    const uint4* src = fdata + (size_t)limg * IMG_U4 + ct * 2048;
    #pragma unroll
    for (int i = 0; i < 8; ++i) tile[t + 256 * i] = src[t + 256 * i];
    __syncthreads();

    const uint2* t64 = (const uint2*)tile;
    float2* zz = scr + wv * PSTRIDE;

    #pragma unroll
    for (int pass = 0; pass < 2; ++pass) {
        const int cp = 2 * wv + pass;       // column-pair 0..7
        float2 uL[8], uR[8], v[8];
        #pragma unroll
        for (int e = 0; e < 8; ++e) {
            int r = j + 64 * e;
            uint2 d = t64[r * 8 + (cp ^ ((r >> 1) & 7))];
            U32H2 a, b; a.u = d.x; b.u = d.y;
            uL[e] = make_float2(__low2float(a.h), __high2float(a.h));
            uR[e] = make_float2(__low2float(b.h), __high2float(b.h));
        }
        #pragma unroll
        for (int side = 0; side < 2; ++side) {
            const int c = ct * 16 + 2 * cp + side;
            float2* uu = side ? uR : uL;
            fft512_wave(zz, uu, v, j);
            const int cw = c > 256 ? 256 : c;
            const float4* w4 = (const float4*)(wfold_dr + (size_t)cw * HW + 8 * j);
            float4 wa = w4[0], wb = w4[1];
            float acc = 0.f;
            acc += (v[0].x*v[0].x + v[0].y*v[0].y) * wa.x;
            acc += (v[1].x*v[1].x + v[1].y*v[1].y) * wa.y;
            acc += (v[2].x*v[2].x + v[2].y*v[2].y) * wa.z;
            acc += (v[3].x*v[3].x + v[3].y*v[3].y) * wa.w;
            acc += (v[4].x*v[4].x + v[4].y*v[4].y) * wb.x;
            acc += (v[5].x*v[5].x + v[5].y*v[5].y) * wb.y;
            acc += (v[6].x*v[6].x + v[6].y*v[6].y) * wb.z;
            acc += (v[7].x*v[7].x + v[7].y*v[7].y) * wb.w;
            #pragma unroll
            for (int off = 32; off > 0; off >>= 1)
                acc += __shfl_down(acc, off, 64);
            if (j == 0 && c <= 256)
                partials[(size_t)(img0 + limg) * NCOL + c] = acc;
            __builtin_amdgcn_wave_barrier();
        }
    }
}

__global__ __launch_bounds__(1024)
void final_reduce(const float* __restrict__ partials,
                  float* __restrict__ out) {
    __shared__ float red[1024];
    const int t = threadIdx.x;
    float acc = 0.f;
    const float4* p4 = (const float4*)partials;
    for (int i = t; i < (NIMG * NCOL) / 4; i += 1024) {   // 24672/4 = 6168
        float4 v = p4[i];
        acc += v.x + v.y + v.z + v.w;
    }
    red[t] = acc;
    __syncthreads();
    #pragma unroll
    for (int s = 512; s > 0; s >>= 1) {
        if (t < s) red[t] += red[t + s];
        __syncthreads();
    }
    if (t == 0) out[0] = red[0] * (1.0f / 25165824.0f);  // / (N*C*H*W)
}

extern "C" void kernel_launch(void* const* d_in, const int* in_sizes, int n_in,
                              void* d_out, int out_size, void* d_ws, size_t ws_size,
                              hipStream_t stream) {
    const float* pred  = (const float*)d_in[0];
    const float* gt    = (const float*)d_in[1];
    const float* bw    = (const float*)d_in[2];
    const float* masks = (const float*)d_in[3];
    float* out = (float*)d_out;

    char* ws = (char*)d_ws;
    float* wmapk    = (float*)ws;                             // 1 MiB
    float* wfold_dr = (float*)(ws + (1 << 20));               // 526,336 B
    float* partials = (float*)(ws + (1 << 20) + (576 << 10)); // 98,688 B
    uint4* fdata    = (uint4*)(ws + (2 << 20));
    const size_t fixed = (2 << 20);
    const size_t img_bytes = (size_t)IMG_U4 * sizeof(uint4);  // 557,056 B

    int chunk = 1;
    if (ws_size > fixed + img_bytes)
        chunk = (int)((ws_size - fixed) / img_bytes);
    if (chunk > NIMG) chunk = NIMG;
    if (chunk < 1) chunk = 1;

    wmapk_kernel<<<(HW * HW) / 256, 256, 0, stream>>>(bw, masks, wmapk);
    wfold_kernel<<<(NCOL * HW + 255) / 256, 256, 0, stream>>>(wmapk, wfold_dr);

    for (int img0 = 0; img0 < NIMG; img0 += chunk) {
        int n = NIMG - img0 < chunk ? NIMG - img0 : chunk;
        rowfft_kernel<<<dim3(16, n), 256, 0, stream>>>(pred, gt, fdata, img0);
        colfft_kernel<<<dim3(17, n), 256, 0, stream>>>(fdata, wfold_dr, partials, img0);
    }

    final_reduce<<<1, 1024, 0, stream>>>(partials, out);
}

// Round 9
// 71.439 us; speedup vs baseline: 1.9445x; 1.9445x over previous
//
#include <hip/hip_runtime.h>
#include <math.h>

#define HW 512
#define LOG2HW 9
#define NIMG 96       // N*C = 32*3
#define NBANDS 16
#define NCOL 257      // rfft columns 0..256
#define PSTRIDE 518   // float2 stride per 512-FFT scratch slice in LDS
#define IMG_U32 (16 * 4096 + 256)   // u32 per image: 16 slabs [rp256][cl16] + c=256 slab
#define TPITCH 72     // colfft staging LDS row pitch (bytes), 8B-aligned, 2-way-free
#define PI_F 3.14159265358979323846f

typedef float v2f __attribute__((ext_vector_type(2)));

// ---------- small complex helpers ----------
__device__ __forceinline__ float2 cadd(float2 a, float2 b){return make_float2(a.x+b.x, a.y+b.y);}
__device__ __forceinline__ float2 csub(float2 a, float2 b){return make_float2(a.x-b.x, a.y-b.y);}
__device__ __forceinline__ float2 cmul(float2 a, float2 b){return make_float2(a.x*b.x - a.y*b.y, a.x*b.y + a.y*b.x);}
__device__ __forceinline__ float2 mul_negi(float2 a){return make_float2(a.y, -a.x);}  // a * (-i)

// octal digit reversal of 9-bit index (involution)
__device__ __forceinline__ int dr9(int p) {
    return ((p & 7) << 6) | (p & 56) | ((p >> 6) & 7);
}

// LDS scratch swizzle (involution, preserves low 2 bits)
__device__ __forceinline__ int swz(int i)  { return i ^ (((i >> 6) & 7) << 2); }

// 8-point DFT, W8 = e^{-2*pi*i/8}
__device__ __forceinline__ void dft8(const float2 u[8], float2 v[8]) {
    const float R = 0.70710678118654752440f;
    float2 s0 = cadd(u[0], u[4]), s1 = cadd(u[2], u[6]);
    float2 d0 = csub(u[0], u[4]), d1 = csub(u[2], u[6]);
    float2 E0 = cadd(s0, s1), E2 = csub(s0, s1);
    float2 ni = mul_negi(d1);
    float2 E1 = cadd(d0, ni), E3 = csub(d0, ni);
    float2 t0 = cadd(u[1], u[5]), t1 = cadd(u[3], u[7]);
    float2 e0 = csub(u[1], u[5]), e1 = csub(u[3], u[7]);
    float2 O0 = cadd(t0, t1), O2 = csub(t0, t1);
    float2 mi = mul_negi(e1);
    float2 O1 = cadd(e0, mi), O3 = csub(e0, mi);
    float2 w1O = make_float2(R * (O1.x + O1.y), R * (O1.y - O1.x));
    float2 w2O = mul_negi(O2);
    float2 w3O = make_float2(R * (O3.y - O3.x), -R * (O3.x + O3.y));
    v[0] = cadd(E0, O0);  v[4] = csub(E0, O0);
    v[1] = cadd(E1, w1O); v[5] = csub(E1, w1O);
    v[2] = cadd(E2, w2O); v[6] = csub(E2, w2O);
    v[3] = cadd(E3, w3O); v[7] = csub(E3, w3O);
}

__device__ __forceinline__ void twiddle_mul8(float2 v[8], float ang) {
    float sn, cs;
    __sincosf(ang, &sn, &cs);
    float2 w1 = make_float2(cs, sn);
    float2 w2 = cmul(w1, w1), w3 = cmul(w2, w1), w4 = cmul(w2, w2);
    float2 w5 = cmul(w3, w2), w6 = cmul(w3, w3), w7 = cmul(w4, w3);
    v[1] = cmul(v[1], w1); v[2] = cmul(v[2], w2); v[3] = cmul(v[3], w3);
    v[4] = cmul(v[4], w4); v[5] = cmul(v[5], w5); v[6] = cmul(v[6], w6);
    v[7] = cmul(v[7], w7);
}

// 512-pt DIF radix-8 FFT, one FFT per WAVE (lane j), wave-private LDS slice.
// Input: u[e] = x[j + 64e]. Output: v[s] = X[dr9(8j+s)]. No workgroup barriers.
__device__ __forceinline__ void fft512_wave(float2* zz, float2 u[8], float2 v[8], int j) {
    dft8(u, v);
    twiddle_mul8(v, -(2.0f * PI_F / 512.0f) * (float)j);
    #pragma unroll
    for (int s = 0; s < 8; ++s) zz[swz(j + 64 * s)] = v[s];
    __builtin_amdgcn_wave_barrier();
    const int sb = j >> 3, r = j & 7;
    #pragma unroll
    for (int e = 0; e < 8; ++e) u[e] = zz[swz(64 * sb + r + 8 * e)];
    __builtin_amdgcn_wave_barrier();
    dft8(u, v);
    twiddle_mul8(v, -(2.0f * PI_F / 64.0f) * (float)r);
    #pragma unroll
    for (int s = 0; s < 8; ++s) zz[swz(64 * sb + r + 8 * s)] = v[s];
    __builtin_amdgcn_wave_barrier();
    #pragma unroll
    for (int e = 0; e < 8; ++e) u[e] = zz[swz(8 * j + e)];
    __builtin_amdgcn_wave_barrier();
    dft8(u, v);
}

// ---------- weight precompute ----------
// Nontemporal mask loads: 16.8 MB streamed once per call, kept OUT of L3 so
// pred/gt (201 MB) + fdata fp8 (26 MB) stay L3-resident across replays.
__global__ void wmapk_kernel(const float* __restrict__ bw,
                             const float* __restrict__ masks,
                             float* __restrict__ wmapk) {
    int idx = blockIdx.x * 256 + threadIdx.x;
    int k1 = idx >> LOG2HW, k2 = idx & (HW - 1);
    int p1 = (k1 + HW / 2) & (HW - 1);
    int p2 = (k2 + HW / 2) & (HW - 1);
    int off = p1 * HW + p2;
    float s = 0.f;
    #pragma unroll
    for (int b = 0; b < NBANDS; ++b)
        s += bw[b] * __builtin_nontemporal_load(&masks[b * HW * HW + off]);
    wmapk[idx] = s;
}

// wfold_dr[c*512 + p]: Hermitian-folded weight for column c at storage
// position p (k1 = dr9(p)); includes ortho norm 1/512^2.
__global__ void wfold_kernel(const float* __restrict__ wmapk,
                             float* __restrict__ wfold_dr) {
    int idx = blockIdx.x * 256 + threadIdx.x;
    if (idx >= NCOL * HW) return;
    int c = idx >> LOG2HW, p = idx & (HW - 1);
    int k1 = dr9(p);
    float s = wmapk[k1 * HW + c];
    if (c >= 1 && c <= 255)
        s += wmapk[((HW - k1) & (HW - 1)) * HW + (HW - c)];
    wfold_dr[idx] = s * (1.0f / (512.0f * 512.0f));
}

// ---------- row pass ----------
// Block = 8 packs (16 rows), wave = one pack (rows 2f re / 2f+1 im).
// Wave-private FFT + natural-order bounce (the 80.8us structure), one
// __syncthreads, then cross-wave Hermitian unpack storing A,B as fp8
// pairs packed in one u32 per (column, row-pair).
// fdata layout: [ct:16][rp:256][cl:16] u32 (64 B/row) + slab16 [rp:256] u32.
// Store mapping (cl=t&15, q=(t>>4)&7, hw=t>>7): each wave-instruction
// covers 4 q-rows x 16 cl = full 64B sectors & full 128B lines (no RMW).
__global__ __launch_bounds__(512, 4)
void rowfft_kernel(const float* __restrict__ pred,
                   const float* __restrict__ gt,
                   unsigned* __restrict__ fdata, int img0) {
    __shared__ float2 z[8 * PSTRIDE];
    const int limg = blockIdx.y;
    const int t = threadIdx.x;
    const int wv = t >> 6, j = t & 63;
    const int img = img0 + limg;
    const int f = blockIdx.x * 8 + wv;          // pack 0..255

    float2* zz = z + wv * PSTRIDE;
    const size_t rbase = ((size_t)img * HW + 2 * f) * HW;
    const float4* pA = (const float4*)(pred + rbase);
    const float4* gA = (const float4*)(gt + rbase);
    const float4* pB = (const float4*)(pred + rbase + HW);
    const float4* gB = (const float4*)(gt + rbase + HW);

    // coalesced float4 loads -> packed err (re=row 2f, im=row 2f+1) in LDS
    #pragma unroll
    for (int it = 0; it < 2; ++it) {
        int c4 = j + 64 * it;                 // float4 chunk 0..127
        float4 a = pA[c4], b = gA[c4], d = pB[c4], e4 = gB[c4];
        float4* dst = (float4*)(zz + swz(4 * c4));
        dst[0] = make_float4(a.x - b.x, d.x - e4.x, a.y - b.y, d.y - e4.y);
        dst[1] = make_float4(a.z - b.z, d.z - e4.z, a.w - b.w, d.w - e4.w);
    }
    __builtin_amdgcn_wave_barrier();

    float2 u[8], v[8];
    #pragma unroll
    for (int e = 0; e < 8; ++e) u[e] = zz[swz(j + 64 * e)];
    __builtin_amdgcn_wave_barrier();
    fft512_wave(zz, u, v, j);
    __builtin_amdgcn_wave_barrier();

    // natural-order bounce: Z[64s+m] = v[s]
    const int m = 8 * (j & 7) + (j >> 3);
    #pragma unroll
    for (int s = 0; s < 8; ++s) zz[swz(64 * s + m)] = v[s];
    __syncthreads();

    // cross-wave Hermitian unpack + fp8 store
    const int cl = t & 15;
    const int q  = (t >> 4) & 7;
    const int hw = t >> 7;                     // 0..3
    const float2* zq = z + q * PSTRIDE;
    unsigned* img_base = fdata + (size_t)limg * IMG_U32;
    const int rpg = blockIdx.x * 8 + q;        // global row-pair index
    #pragma unroll
    for (int kb = 0; kb < 4; ++kb) {
        int c = kb * 64 + hw * 16 + cl;        // 0..255
        float2 Zc = zq[swz(c)];
        float2 Zn = zq[swz((HW - c) & (HW - 1))];
        float ax = 0.5f * (Zc.x + Zn.x), ay = 0.5f * (Zc.y - Zn.y);
        float bx = 0.5f * (Zc.y + Zn.y), by = 0.5f * (Zn.x - Zc.x);
        int w0 = __builtin_amdgcn_cvt_pk_fp8_f32(ax, ay, 0, false);
        int w1 = __builtin_amdgcn_cvt_pk_fp8_f32(bx, by, w0, true);
        img_base[(kb * 4 + hw) * 4096 + rpg * 16 + cl] = (unsigned)w1;
    }
    if (t < 8) {                               // c = 256 tail (q = t)
        const float2* zq2 = z + t * PSTRIDE;
        float2 Zc = zq2[swz(256)];
        int w0 = __builtin_amdgcn_cvt_pk_fp8_f32(Zc.x, 0.f, 0, false);
        int w1 = __builtin_amdgcn_cvt_pk_fp8_f32(Zc.y, 0.f, w0, true);
        img_base[16 * 4096 + blockIdx.x * 8 + t] = (unsigned)w1;
    }
}

// ---------- column pass ----------
// Block per ct slab: stage 16 KB contiguous -> LDS (72 B padded rows),
// then 4 waves x 4 columns: wave-private radix-8 FFT on fp8-decoded
// column, weighted power (digit-reversed folded weights), shfl reduce.
__global__ __launch_bounds__(256)
void colfft_kernel(const unsigned* __restrict__ fdata,
                   const float* __restrict__ wfold_dr,
                   float* __restrict__ partials, int img0) {
    __shared__ char tileb[256 * TPITCH];       // 18 KiB
    __shared__ float2 scr[4 * PSTRIDE];
    const int limg = blockIdx.y;
    const int ct = blockIdx.x;                 // 0..16
    const int t = threadIdx.x;
    const int wv = t >> 6, j = t & 63;
    const unsigned* fimg = fdata + (size_t)limg * IMG_U32;
    float2* zz = scr + wv * PSTRIDE;

    if (ct < 16) {
        const uint2* src = (const uint2*)(fimg + ct * 4096);   // 2048 uint2
        #pragma unroll
        for (int k = 0; k < 8; ++k) {
            int i = t + 256 * k;
            int rp = i >> 3, s8 = i & 7;
            *(uint2*)(tileb + rp * TPITCH + s8 * 8) = src[i];
        }
        __syncthreads();

        #pragma unroll
        for (int pass = 0; pass < 4; ++pass) {
            const int cl = wv + 4 * pass;      // 0..15
            const int c = ct * 16 + cl;
            float2 u[8], v[8];
            #pragma unroll
            for (int e = 0; e < 8; ++e) {
                int r = j + 64 * e;
                unsigned hs = *(const unsigned short*)
                    (tileb + (r >> 1) * TPITCH + cl * 4 + (r & 1) * 2);
                v2f d = __builtin_amdgcn_cvt_pk_f32_fp8((int)hs, false);
                u[e] = make_float2(d.x, d.y);
            }
            fft512_wave(zz, u, v, j);
            const float4* w4 = (const float4*)(wfold_dr + (size_t)c * HW + 8 * j);
            float4 wa = w4[0], wb = w4[1];
            float acc = 0.f;
            acc += (v[0].x*v[0].x + v[0].y*v[0].y) * wa.x;
            acc += (v[1].x*v[1].x + v[1].y*v[1].y) * wa.y;
            acc += (v[2].x*v[2].x + v[2].y*v[2].y) * wa.z;
            acc += (v[3].x*v[3].x + v[3].y*v[3].y) * wa.w;
            acc += (v[4].x*v[4].x + v[4].y*v[4].y) * wb.x;
            acc += (v[5].x*v[5].x + v[5].y*v[5].y) * wb.y;
            acc += (v[6].x*v[6].x + v[6].y*v[6].y) * wb.z;
            acc += (v[7].x*v[7].x + v[7].y*v[7].y) * wb.w;
            #pragma unroll
            for (int off = 32; off > 0; off >>= 1)
                acc += __shfl_down(acc, off, 64);
            if (j == 0)
                partials[(size_t)(img0 + limg) * NCOL + c] = acc;
            __builtin_amdgcn_wave_barrier();
        }
    } else if (wv == 0) {                      // c = 256 column, contiguous
        const unsigned short* s16 = (const unsigned short*)(fimg + 16 * 4096);
        float2 u[8], v[8];
        #pragma unroll
        for (int e = 0; e < 8; ++e) {
            unsigned hs = s16[j + 64 * e];
            v2f d = __builtin_amdgcn_cvt_pk_f32_fp8((int)hs, false);
            u[e] = make_float2(d.x, d.y);
        }
        fft512_wave(zz, u, v, j);
        const float4* w4 = (const float4*)(wfold_dr + (size_t)256 * HW + 8 * j);
        float4 wa = w4[0], wb = w4[1];
        float acc = 0.f;
        acc += (v[0].x*v[0].x + v[0].y*v[0].y) * wa.x;
        acc += (v[1].x*v[1].x + v[1].y*v[1].y) * wa.y;
        acc += (v[2].x*v[2].x + v[2].y*v[2].y) * wa.z;
        acc += (v[3].x*v[3].x + v[3].y*v[3].y) * wa.w;
        acc += (v[4].x*v[4].x + v[4].y*v[4].y) * wb.x;
        acc += (v[5].x*v[5].x + v[5].y*v[5].y) * wb.y;
        acc += (v[6].x*v[6].x + v[6].y*v[6].y) * wb.z;
        acc += (v[7].x*v[7].x + v[7].y*v[7].y) * wb.w;
        #pragma unroll
        for (int off = 32; off > 0; off >>= 1)
            acc += __shfl_down(acc, off, 64);
        if (j == 0)
            partials[(size_t)(img0 + limg) * NCOL + 256] = acc;
    }
}

__global__ __launch_bounds__(1024)
void final_reduce(const float* __restrict__ partials,
                  float* __restrict__ out) {
    __shared__ float red[1024];
    const int t = threadIdx.x;
    float acc = 0.f;
    const float4* p4 = (const float4*)partials;
    for (int i = t; i < (NIMG * NCOL) / 4; i += 1024) {   // 24672/4 = 6168
        float4 v = p4[i];
        acc += v.x + v.y + v.z + v.w;
    }
    red[t] = acc;
    __syncthreads();
    #pragma unroll
    for (int s = 512; s > 0; s >>= 1) {
        if (t < s) red[t] += red[t + s];
        __syncthreads();
    }
    if (t == 0) out[0] = red[0] * (1.0f / 25165824.0f);  // / (N*C*H*W)
}

extern "C" void kernel_launch(void* const* d_in, const int* in_sizes, int n_in,
                              void* d_out, int out_size, void* d_ws, size_t ws_size,
                              hipStream_t stream) {
    const float* pred  = (const float*)d_in[0];
    const float* gt    = (const float*)d_in[1];
    const float* bw    = (const float*)d_in[2];
    const float* masks = (const float*)d_in[3];
    float* out = (float*)d_out;

    char* ws = (char*)d_ws;
    float* wmapk    = (float*)ws;                             // 1 MiB
    float* wfold_dr = (float*)(ws + (1 << 20));               // 526,336 B
    float* partials = (float*)(ws + (1 << 20) + (576 << 10)); // 98,688 B
    unsigned* fdata = (unsigned*)(ws + (2 << 20));
    const size_t fixed = (2 << 20);
    const size_t img_bytes = (size_t)IMG_U32 * 4;             // 263,168 B

    int chunk = 1;
    if (ws_size > fixed + img_bytes)
        chunk = (int)((ws_size - fixed) / img_bytes);
    if (chunk > NIMG) chunk = NIMG;
    if (chunk < 1) chunk = 1;

    wmapk_kernel<<<(HW * HW) / 256, 256, 0, stream>>>(bw, masks, wmapk);
    wfold_kernel<<<(NCOL * HW + 255) / 256, 256, 0, stream>>>(wmapk, wfold_dr);

    for (int img0 = 0; img0 < NIMG; img0 += chunk) {
        int n = NIMG - img0 < chunk ? NIMG - img0 : chunk;
        rowfft_kernel<<<dim3(HW / 16, n), 512, 0, stream>>>(pred, gt, fdata, img0);
        colfft_kernel<<<dim3(17, n), 256, 0, stream>>>(fdata, wfold_dr, partials, img0);
    }

    final_reduce<<<1, 1024, 0, stream>>>(partials, out);
}